// Round 2
// baseline (1223.080 us; speedup 1.0000x reference)
//
#include <hip/hip_runtime.h>

// out[b,z] = sum_ij C[z,i,j] x[b,i] y[b,j],  B=256, D=128, Z=8256 = 516 z16-tiles
// Wave-independent j-split: wave w owns j in [32w, 32w+32). B-fragments of C are
// loaded straight from global into registers (no LDS staging, no barriers in the
// i-loop). A-fragments = y (bf16, resident in 64 VGPRs, all 256 b rows per wave).
// Per i: S_partial = mfma(yf, cfrag); acc += x[b,i] * S_partial (fold is linear,
// so per-wave j-partials just add up in the final atomic flush).

typedef __bf16 bf16x8 __attribute__((ext_vector_type(8)));
typedef float floatx4 __attribute__((ext_vector_type(4)));

#define TPB 256
#define GRID 512   // 512 WGs * 129 quanta = 66048 = 516 z16-tiles * 128 i

__global__ void xpose_kernel(const float* __restrict__ xg, float* __restrict__ xTg) {
    const int n = blockIdx.x * 256 + threadIdx.x;   // n = i*256 + b
    const int i = n >> 8, b = n & 255;
    xTg[n] = xg[b * 128 + i];
}

template<bool XT>
__global__ __launch_bounds__(TPB, 2)
void rtp_v3(const float* __restrict__ xg, const float* __restrict__ yg,
            const float* __restrict__ Cg, const float* __restrict__ xTg,
            float* __restrict__ out)
{
    __shared__ float scratch[256 * 16];   // (b_local, z_local) cross-wave reduce tile

    const int tid  = threadIdx.x;
    const int w    = tid >> 6;            // wave id = j-chunk
    const int lane = tid & 63;
    const int l15  = lane & 15;
    const int quad = lane >> 4;

    // zero reduce tile (bank-conflict-free: lane -> bank tid&31)
#pragma unroll
    for (int c = 0; c < 16; ++c) scratch[c * 256 + tid] = 0.f;

    // Y fragments: yf[mb] lane reg j = y[mb*16 + l15][w*32 + quad*8 + j]
    bf16x8 yf[16];
    {
        const float* ybase = yg + l15 * 128 + w * 32 + quad * 8;
#pragma unroll
        for (int mb = 0; mb < 16; ++mb) {
            const floatx4 f0 = *(const floatx4*)(ybase + mb * 2048);
            const floatx4 f1 = *(const floatx4*)(ybase + mb * 2048 + 4);
            bf16x8 v;
            v[0] = (__bf16)f0[0]; v[1] = (__bf16)f0[1];
            v[2] = (__bf16)f0[2]; v[3] = (__bf16)f0[3];
            v[4] = (__bf16)f1[0]; v[5] = (__bf16)f1[1];
            v[6] = (__bf16)f1[2]; v[7] = (__bf16)f1[3];
            yf[mb] = v;
        }
    }

    __syncthreads();   // scratch zero visible before first flush's ds-adds

    int q        = (int)blockIdx.x * 129;
    const int q1 = q + 129;

    const floatx4 z4 = {0.f, 0.f, 0.f, 0.f};

    while (q < q1) {
        const int z16  = q >> 7;
        const int i0   = q & 127;
        const int rem  = q1 - q;
        const int ilen = (128 - i0) < rem ? (128 - i0) : rem;

        // lane's C base: C[(z16*16 + l15)][i0][w*32 + quad*8]
        const float* cb = Cg + (((size_t)(z16 * 16 + l15)) << 14)
                             + (size_t)i0 * 128 + w * 32 + quad * 8;

        floatx4 acc[16];
#pragma unroll
        for (int mb = 0; mb < 16; ++mb) acc[mb] = z4;

        // register double-buffer prefetch of C fragments (never drained: no barriers)
        floatx4 pv[2][2];
        pv[0][0] = __builtin_nontemporal_load((const floatx4*)cb);
        pv[0][1] = __builtin_nontemporal_load((const floatx4*)(cb + 4));
        if (ilen > 1) {
            pv[1][0] = __builtin_nontemporal_load((const floatx4*)(cb + 128));
            pv[1][1] = __builtin_nontemporal_load((const floatx4*)(cb + 132));
        }

        for (int t = 0; t < ilen; ++t) {
            const int buf = t & 1;
            const floatx4 f0 = pv[buf][0], f1 = pv[buf][1];
            bf16x8 bfrag;
            bfrag[0] = (__bf16)f0[0]; bfrag[1] = (__bf16)f0[1];
            bfrag[2] = (__bf16)f0[2]; bfrag[3] = (__bf16)f0[3];
            bfrag[4] = (__bf16)f1[0]; bfrag[5] = (__bf16)f1[1];
            bfrag[6] = (__bf16)f1[2]; bfrag[7] = (__bf16)f1[3];

            if (t + 2 < ilen) {
                const float* p = cb + (size_t)(t + 2) * 128;
                pv[buf][0] = __builtin_nontemporal_load((const floatx4*)p);
                pv[buf][1] = __builtin_nontemporal_load((const floatx4*)(p + 4));
            }

            const int i = i0 + t;
#pragma unroll
            for (int mb = 0; mb < 16; ++mb) {
                floatx4 S = __builtin_amdgcn_mfma_f32_16x16x32_bf16(yf[mb], bfrag, z4, 0, 0, 0);
                floatx4 xv;
                if (XT) {
                    xv = *(const floatx4*)(xTg + i * 256 + mb * 16 + quad * 4);
                } else {
                    const float* xp = xg + (mb * 16 + quad * 4) * 128 + i;
                    xv[0] = xp[0]; xv[1] = xp[128]; xv[2] = xp[256]; xv[3] = xp[384];
                }
                acc[mb] += xv * S;   // fold x[b,i]; rows b = mb*16 + quad*4 + r
            }
        }

        // ---- flush: reduce 4 waves' partials in LDS, then atomics to out ----
#pragma unroll
        for (int mb = 0; mb < 16; ++mb) {
            const int row = mb * 16 + quad * 4;
#pragma unroll
            for (int r = 0; r < 4; ++r)
                atomicAdd(&scratch[(row + r) * 16 + l15], acc[mb][r]);
        }
        __syncthreads();
        {
            float* srow = &scratch[tid * 16];   // b_local = tid
            floatx4 s0 = *(floatx4*)(srow);
            floatx4 s1 = *(floatx4*)(srow + 4);
            floatx4 s2 = *(floatx4*)(srow + 8);
            floatx4 s3 = *(floatx4*)(srow + 12);
            float* orow = out + (size_t)tid * 8256 + z16 * 16;
            atomicAdd(orow + 0,  s0[0]); atomicAdd(orow + 1,  s0[1]);
            atomicAdd(orow + 2,  s0[2]); atomicAdd(orow + 3,  s0[3]);
            atomicAdd(orow + 4,  s1[0]); atomicAdd(orow + 5,  s1[1]);
            atomicAdd(orow + 6,  s1[2]); atomicAdd(orow + 7,  s1[3]);
            atomicAdd(orow + 8,  s2[0]); atomicAdd(orow + 9,  s2[1]);
            atomicAdd(orow + 10, s2[2]); atomicAdd(orow + 11, s2[3]);
            atomicAdd(orow + 12, s3[0]); atomicAdd(orow + 13, s3[1]);
            atomicAdd(orow + 14, s3[2]); atomicAdd(orow + 15, s3[3]);
            *(floatx4*)(srow)      = z4;   // re-zero for next run
            *(floatx4*)(srow + 4)  = z4;
            *(floatx4*)(srow + 8)  = z4;
            *(floatx4*)(srow + 12) = z4;
        }
        __syncthreads();
        q += ilen;
    }
}

extern "C" void kernel_launch(void* const* d_in, const int* in_sizes, int n_in,
                              void* d_out, int out_size, void* d_ws, size_t ws_size,
                              hipStream_t stream) {
    (void)in_sizes; (void)n_in;
    const float* x = (const float*)d_in[0];
    const float* y = (const float*)d_in[1];
    const float* C = (const float*)d_in[2];
    float* out = (float*)d_out;

    hipMemsetAsync(out, 0, (size_t)out_size * sizeof(float), stream);

    if (ws_size >= 32768 * sizeof(float)) {
        float* xTg = (float*)d_ws;
        xpose_kernel<<<128, 256, 0, stream>>>(x, xTg);
        rtp_v3<true><<<GRID, TPB, 0, stream>>>(x, y, C, xTg, out);
    } else {
        rtp_v3<false><<<GRID, TPB, 0, stream>>>(x, y, C, x, out);
    }
}